// Round 14
// baseline (428.948 us; speedup 1.0000x reference)
//
#include <hip/hip_runtime.h>
#include <hip/hip_bf16.h>

using bf16x8 = __attribute__((ext_vector_type(8))) short;
using f32x4  = __attribute__((ext_vector_type(4))) float;

#define DEVI __device__ __forceinline__

DEVI unsigned short bf16r(float f)
{
    return __builtin_bit_cast(unsigned short, __float2bfloat16(f));
}

DEVI bf16x8 cvt8(const f32x4 a, const f32x4 b)
{
    bf16x8 r;
#pragma unroll
    for (int j = 0; j < 4; ++j) {
        r[j]     = (short)bf16r(a[j]);
        r[4 + j] = (short)bf16r(b[j]);
    }
    return r;
}

// ---------------- gather: x[b][:] = bf16(E[inp[b]][:]) ----------------
__global__ __launch_bounds__(256) void k_gather(const float* __restrict__ E,
                                                const int* __restrict__ inp,
                                                unsigned short* __restrict__ x)
{
    const int b = blockIdx.x;
    const long r = inp[b];
    const f32x4 v = ((const f32x4*)(E + r * 1024L))[threadIdx.x];
    ushort4 o;
    o.x = bf16r(v[0]); o.y = bf16r(v[1]); o.z = bf16r(v[2]); o.w = bf16r(v[3]);
    ((ushort4*)(x + (long)b * 1024L))[threadIdx.x] = o;
}

// ---------------- fp32 -> bf16 bulk convert ----------------
__global__ __launch_bounds__(256) void k_cvtn(const float* __restrict__ in,
                                              unsigned short* __restrict__ out)
{
    const long i = (blockIdx.x * 256L + threadIdx.x) * 8;
    const f32x4 a = *(const f32x4*)(in + i);
    const f32x4 b = *(const f32x4*)(in + i + 4);
    *(bf16x8*)(out + i) = cvt8(a, b);
}

// =====================================================================
// GEMM core (R5 skeleton, retiled): BM=256 x BN=128, BK=32, 256 threads
// (4 waves 2x2; per-wave 128x64 out, acc[8][4], 32 MFMA/K-tile).
// Per K-tile VMEM: A 16KB bf16 + B 16KB fp32 = 32KB for the same FLOPs
// R5 bought with 48KB (B amortized over 2x A-rows).
//   A LDS: 256 rows x 64B (4 granules), slot = j ^ ((row>>1)&3)
//   B LDS: 128 rows x 128B (8 granules fp32), slot = s ^ (row&7)
// Both staged via global_load_lds w16: swizzle pre-applied to the GLOBAL
// source, linear LDS dest (rule #21); read applies the same XOR (<=2-way
// bank alias = free, m136). B converted fp32->bf16 at register-read.
// 2-barrier loop: bar -> 8 DMAs -> bar(vmcnt drain) -> MFMA. 32KB LDS,
// VGPR ~170 -> 3 blocks/CU (R5's proven occupancy regime).
// =====================================================================

DEVI void mfma_tile256(const char* sA, const char* sB, int l, int wr, int wc,
                       f32x4 (&acc)[8][4])
{
    const int j = l >> 4;
    bf16x8 af[8], bq[4];
#pragma unroll
    for (int m = 0; m < 8; ++m) {
        const int ar = wr * 128 + m * 16 + (l & 15);
        af[m] = *(const bf16x8*)(sA + ar * 64 + ((j ^ ((ar >> 1) & 3)) << 4));
    }
#pragma unroll
    for (int n = 0; n < 4; ++n) {
        const int br = wc * 64 + n * 16 + (l & 15);
        const int rx = br & 7;
        const f32x4 lo = *(const f32x4*)(sB + br * 128 + (((2 * j)     ^ rx) << 4));
        const f32x4 hi = *(const f32x4*)(sB + br * 128 + (((2 * j + 1) ^ rx) << 4));
        bq[n] = cvt8(lo, hi);
    }
#pragma unroll
    for (int m = 0; m < 8; ++m)
#pragma unroll
        for (int n = 0; n < 4; ++n)
            acc[m][n] = __builtin_amdgcn_mfma_f32_16x16x32_bf16(
                af[m], bq[n], acc[m][n], 0, 0, 0);
}

template <bool CLAMP>
DEVI void gemm_core256(const unsigned short* __restrict__ A, long lda, long arow0,
                       const float* __restrict__ B, long ldb, long brow0,
                       long bmax, int nt, long kbase, int t,
                       char* sA, char* sB, f32x4 (&acc)[8][4])
{
    const int l = t & 63;
    const int wr = (t >> 7) & 1, wc = (t >> 6) & 1;

    // A: 256 rows x 4 granules = 1024 -> 4/thread, source pre-swizzled.
    const unsigned short* ap[4];
#pragma unroll
    for (int i = 0; i < 4; ++i) {
        const int g = i * 256 + t, row = g >> 2, j = g & 3;
        ap[i] = A + (arow0 + row) * lda + kbase + (long)((j ^ ((row >> 1) & 3)) * 8);
    }
    // B: 128 rows x 8 granules (4 fp32 = 16B) = 1024 -> 4/thread.
    const float* bp[4];
#pragma unroll
    for (int i = 0; i < 4; ++i) {
        const int g = i * 256 + t, row = g >> 3, s = g & 7;
        long br = brow0 + row;
        if (CLAMP) br = (br < bmax) ? br : (bmax - 1);
        bp[i] = B + br * ldb + kbase + (long)((s ^ (row & 7)) * 4);
    }

    for (int ti = 0; ti < nt; ++ti) {
        __syncthreads();                       // WAR: prev tile fully consumed
#pragma unroll
        for (int i = 0; i < 4; ++i) {
            __builtin_amdgcn_global_load_lds(
                (const __attribute__((address_space(1))) void*)(ap[i]),
                (__attribute__((address_space(3))) void*)(sA + (i * 256 + t) * 16),
                16, 0, 0);
            ap[i] += 32;
        }
#pragma unroll
        for (int i = 0; i < 4; ++i) {
            __builtin_amdgcn_global_load_lds(
                (const __attribute__((address_space(1))) void*)(bp[i]),
                (__attribute__((address_space(3))) void*)(sB + (i * 256 + t) * 16),
                16, 0, 0);
            bp[i] += 32;
        }
        __syncthreads();                       // RAW: vmcnt drained, tile visible
        mfma_tile256(sA, sB, l, wr, wc, acc);
    }
}

// ---------------- gates GEMM: 384 = 8 x 48 blocks (exact, bijective) --------
// L = xcd*48 + slot; z = L>>7 (3 chunks x 128); mtile = (L&127)&1,
// ntile = (L&127)>>1. mtile pairs are L-consecutive -> same XCD L2.
__global__ __launch_bounds__(256, 3) void k_gates(
    const unsigned short* __restrict__ xb, const float* __restrict__ Wx,
    const unsigned short* __restrict__ h0b, const float* __restrict__ Wh,
    float* __restrict__ g0, float* __restrict__ g1, float* __restrict__ g2)
{
    __shared__ __align__(16) char sA[16384];
    __shared__ __align__(16) char sB[16384];
    const int t = threadIdx.x;
    const int bid = blockIdx.x;
    const int xcd = bid & 7, slot = bid >> 3;
    const int L = xcd * 48 + slot;             // 0..383, bijective
    const int z = L >> 7;
    const int rest = L & 127;
    const int mtile = rest & 1;
    const int ntile = rest >> 1;               // 0..63

    const unsigned short* A; const float* B; long lda, ldb, kbase; float* C;
    if (z == 0)      { A = xb;  lda = 1024; B = Wx; ldb = 1024; kbase = 0;    C = g0; }
    else if (z == 1) { A = h0b; lda = 2048; B = Wh; ldb = 2048; kbase = 0;    C = g1; }
    else             { A = h0b; lda = 2048; B = Wh; ldb = 2048; kbase = 1024; C = g2; }

    f32x4 acc[8][4] = {};
    gemm_core256<false>(A, lda, (long)mtile * 256, B, ldb, (long)ntile * 128,
                        1L << 40, 32, kbase, t, sA, sB, acc);

    const int l = t & 63;
    const int wr = (t >> 7) & 1, wc = (t >> 6) & 1;
    const int lc = l & 15, r4 = (l >> 4) * 4;
#pragma unroll
    for (int n = 0; n < 4; ++n) {
        const long col = (long)ntile * 128 + wc * 64 + n * 16 + lc;
#pragma unroll
        for (int m = 0; m < 8; ++m) {
            const long row = (long)mtile * 256 + wr * 128 + m * 16 + r4;
#pragma unroll
            for (int r = 0; r < 4; ++r)
                C[(row + r) * 8192 + col] = acc[m][n][r];
        }
    }
}

// ---------------- decoder GEMM: out = hx @ Wd^T + bd (fp32 Wd direct) -------
// Grid 800 = 8 x 100; L = xcd*100 + slot covers 0..799 contiguously;
// blocks with L >= 786 exit (uniform, before any barrier). mtile = L&1,
// ntile = L>>1 in 0..392 — bijective by construction.
__global__ __launch_bounds__(256, 3) void k_dec(
    const unsigned short* __restrict__ hxb, const float* __restrict__ Wd,
    const float* __restrict__ bd, float* __restrict__ out)
{
    __shared__ __align__(16) char sA[16384];
    __shared__ __align__(16) char sB[16384];
    const int t = threadIdx.x;
    const int bid = blockIdx.x;
    const int xcd = bid & 7, slot = bid >> 3;
    const int L = xcd * 100 + slot;
    if (L >= 786) return;                      // block-uniform, pre-barrier
    const int mtile = L & 1;
    const int ntile = L >> 1;                  // 0..392
    const long N = 50257;

    f32x4 acc[8][4] = {};
    gemm_core256<true>(hxb, 2048, (long)mtile * 256, Wd, 2048, (long)ntile * 128,
                       N, 64, 0, t, sA, sB, acc);

    const int l = t & 63;
    const int wr = (t >> 7) & 1, wc = (t >> 6) & 1;
    const int lc = l & 15, r4 = (l >> 4) * 4;
#pragma unroll
    for (int n = 0; n < 4; ++n) {
        const long col = (long)ntile * 128 + wc * 64 + n * 16 + lc;
        if (col >= N) continue;
        const float bias = bd[col];
#pragma unroll
        for (int m = 0; m < 8; ++m) {
            const long row = (long)mtile * 256 + wr * 128 + m * 16 + r4;
#pragma unroll
            for (int r = 0; r < 4; ++r)
                out[(row + r) * N + col] = acc[m][n][r] + bias;
        }
    }
}

// ---------------- elementwise LSTM cell: combine 3 partials + biases ----------------
__global__ __launch_bounds__(256) void k_lstm(
    const float* __restrict__ g0, const float* __restrict__ g1,
    const float* __restrict__ g2, const float* __restrict__ bx,
    const float* __restrict__ bh, const float* __restrict__ c0,
    float* __restrict__ hx, float* __restrict__ cx,
    unsigned short* __restrict__ hxb)
{
    const int i = blockIdx.x * 256 + threadIdx.x;
    const int b = i >> 9;
    const int hc = (i & 511) << 2;
    const long base = (long)b * 8192;

    f32x4 g[4];
#pragma unroll
    for (int gi = 0; gi < 4; ++gi) {
        const long off = base + gi * 2048 + hc;
        const int boff = gi * 2048 + hc;
        g[gi] = *(const f32x4*)(g0 + off);
        g[gi] += *(const f32x4*)(g1 + off);
        g[gi] += *(const f32x4*)(g2 + off);
        g[gi] += *(const f32x4*)(bx + boff);
        g[gi] += *(const f32x4*)(bh + boff);
    }
    const f32x4 c0v = *(const f32x4*)(c0 + (long)b * 2048 + hc);

    f32x4 cv, hv;
    ushort4 hb;
#pragma unroll
    for (int j = 0; j < 4; ++j) {
        const float fg = 1.f / (1.f + __expf(-g[0][j]));
        const float ig = 1.f / (1.f + __expf(-g[1][j]));
        const float og = 1.f / (1.f + __expf(-g[2][j]));
        const float e2 = __expf(2.f * g[3][j]);
        const float ct = 1.f - 2.f / (e2 + 1.f);
        const float c  = fg * c0v[j] + ig * ct;
        const float e2c = __expf(2.f * c);
        const float th  = 1.f - 2.f / (e2c + 1.f);
        cv[j] = c;
        hv[j] = og * th;
    }
    hb.x = bf16r(hv[0]); hb.y = bf16r(hv[1]); hb.z = bf16r(hv[2]); hb.w = bf16r(hv[3]);

    const long o = (long)b * 2048 + hc;
    *(f32x4*)(cx + o) = cv;
    *(f32x4*)(hx + o) = hv;
    *(ushort4*)(hxb + o) = hb;
}

// ---------------- launch ----------------
extern "C" void kernel_launch(void* const* d_in, const int* in_sizes, int n_in,
                              void* d_out, int out_size, void* d_ws, size_t ws_size,
                              hipStream_t stream)
{
    const int*   inp = (const int*)d_in[0];
    const float* h0  = (const float*)d_in[1];
    const float* c0  = (const float*)d_in[2];
    const float* E   = (const float*)d_in[3];
    const float* Wx  = (const float*)d_in[4];   // (8192,1024)
    const float* bx  = (const float*)d_in[5];
    const float* Wh  = (const float*)d_in[6];   // (8192,2048)
    const float* bh  = (const float*)d_in[7];
    const float* Wd  = (const float*)d_in[8];   // (50257,2048)
    const float* bd  = (const float*)d_in[9];

    float* out = (float*)d_out;                 // [512][50257]
    float* hx  = out + 512L * 50257L;           // [512][2048]
    float* cx  = hx + 512L * 2048L;

    // Scratch in the out region (all consumed before k_dec overwrites out):
    //   xb @ 0 (0.5MB), g0 @ 1M floats, g1 @ 5M, g2 @ 9M, h0b @ 13M floats.
    unsigned short* xb  = (unsigned short*)out;
    float* g0 = out + (1L << 20);
    float* g1 = out + (5L << 20);
    float* g2 = out + (9L << 20);
    unsigned short* h0b = (unsigned short*)(out + (13L << 20));
    // hxb read during k_dec (which writes out) -> lives in d_ws.
    unsigned short* hxb = (unsigned short*)d_ws;

    k_gather<<<512, 256, 0, stream>>>(E, inp, xb);
    k_cvtn<<<512, 256, 0, stream>>>(h0, h0b);

    k_gates<<<384, 256, 0, stream>>>(xb, Wx, h0b, Wh, g0, g1, g2);

    k_lstm<<<1024, 256, 0, stream>>>(g0, g1, g2, bx, bh, c0, hx, cx, hxb);

    k_dec<<<800, 256, 0, stream>>>(hxb, Wd, bd, out);
}